// Round 6
// baseline (356.440 us; speedup 1.0000x reference)
//
#include <hip/hip_runtime.h>
#include <math.h>

// Problem constants
#define DD    2048   // model dim
#define EE    64     // num experts
#define NTOK  8192   // B*T

// Output layout (all read back as float32 by harness):
//   router_probs [4,2048,64]  -> 524288 floats @ 0
//   top_k_indices [4,2048,2]  -> 16384 floats  @ 524288
//   exp_mask [2, 8192, 64]    -> 1048576 floats @ 540672
#define PROB_OFF 0
#define IDX_OFF  524288
#define MASK_OFF 540672
#define MASK_K_STRIDE (NTOK * EE)   // 524288

// ---------------------------------------------------------------------------
// GEMM. lanes 0..31 = gate, lanes 32..63 = noise; each lane owns 2 adjacent
// expert columns. x is kept on the VECTOR path (asm launder -> vmcnt,
// out-of-order, pipelinable); all 64 lanes share the address -> TA broadcast.
//
// R5 failed because VGPR_Count=36 forced serialized load->use chains
// (4218 cyc/iter). This version gives the scheduler a 16-k macro-iteration
// whose 48 loads (16 x float4 + 16 w float2) are all independent, plus a
// 128-VGPR budget (__launch_bounds__(256,4)) to keep them in flight.
// Each token consumes its x cache lines with back-to-back float4 loads
// (MSHR-merged), so the 8KB-stride L1 set-aliasing no longer costs L2
// traffic. FMAs are scalar fmaf on accx/accy -> pure v_fma_f32, no splat
// movs. No atomics; k-split partials in disjoint ws regions.
// ---------------------------------------------------------------------------
template <int KSPLIT, int TT, int KC>
__global__ __launch_bounds__(256, 4) void router_gemm(
    const float* __restrict__ x,        // [NTOK][DD]
    const float* __restrict__ w_gate,   // [DD][EE]
    const float* __restrict__ w_noise,  // [DD][EE]
    float* __restrict__ part)           // [NTOK][KSPLIT][2*EE]
{
  constexpr int KR = DD / KSPLIT;

  const int lane = threadIdx.x & 63;
  const int wid  = threadIdx.x >> 6;              // 0..3 (token subtile)
  const int tok0 = blockIdx.x * (4 * TT) + wid * TT;
  const int ks   = blockIdx.y;
  const int k0   = ks * KR;
  const int le   = lane & 31;

  const float* __restrict__ W =
      ((lane & 32) ? w_noise : w_gate) + 2 * le + (size_t)k0 * EE;

  // x base: launder into VGPR so loads stay on the vector path (vmcnt).
  const float* xb = x + (size_t)tok0 * DD + k0;
  asm("" : "+v"(xb));

  float accx[TT], accy[TT];
#pragma unroll
  for (int t = 0; t < TT; ++t) { accx[t] = 0.0f; accy[t] = 0.0f; }

  for (int k = 0; k < KR; k += KC) {
    // ---- issue all independent loads for this macro-iteration ----
    float4 xv[TT][KC / 4];
#pragma unroll
    for (int t = 0; t < TT; ++t)
#pragma unroll
      for (int c = 0; c < KC / 4; ++c)
        xv[t][c] = *reinterpret_cast<const float4*>(
            xb + (size_t)t * DD + k + 4 * c);

    float2 wv[KC];
#pragma unroll
    for (int u = 0; u < KC; ++u)
      wv[u] = *reinterpret_cast<const float2*>(W + (size_t)(k + u) * EE);

    // ---- compute: 2*TT*KC scalar v_fma_f32 ----
#pragma unroll
    for (int t = 0; t < TT; ++t) {
#pragma unroll
      for (int u = 0; u < KC; ++u) {
        const float4 q = xv[t][u >> 2];
        const float xs = ((u & 3) == 0) ? q.x : ((u & 3) == 1) ? q.y
                       : ((u & 3) == 2) ? q.z : q.w;
        accx[t] = fmaf(xs, wv[u].x, accx[t]);
        accy[t] = fmaf(xs, wv[u].y, accy[t]);
      }
    }
  }

  // store: token-major partials, gate cols at words 0..63, noise at 64..127
  float* o = part + ((size_t)tok0 * KSPLIT + ks) * (2 * EE) +
             ((lane & 32) ? EE : 0) + 2 * le;
#pragma unroll
  for (int t = 0; t < TT; ++t) {
    float2 v; v.x = accx[t]; v.y = accy[t];
    *reinterpret_cast<float2*>(o + (size_t)t * KSPLIT * (2 * EE)) = v;
  }
}

// ---------------------------------------------------------------------------
// Epilogue: one wave per token. Sum ksplit partials (contiguous per token),
// softplus-noise, top-2 (jax tie semantics: desc value, asc index), softmax
// over 2, scatter probs + indices + one-hot masks.
// ---------------------------------------------------------------------------
__global__ __launch_bounds__(256) void router_epilogue(
    const float* __restrict__ part,      // [NTOK][ksplit][2*EE]
    const float* __restrict__ noise_eps, // [NTOK][EE]
    float* __restrict__ out, int ksplit)
{
  const int t    = blockIdx.x * 4 + (threadIdx.x >> 6);
  const int lane = threadIdx.x & 63;

  const float* p = part + (size_t)t * ksplit * (2 * EE);
  float g = 0.0f, nraw = 0.0f;
  for (int s = 0; s < ksplit; ++s) {
    g    += p[s * (2 * EE) + lane];
    nraw += p[s * (2 * EE) + EE + lane];
  }
  const float ep = noise_eps[(size_t)t * EE + lane];

  // softplus(nraw) = max(nraw,0) + log1p(exp(-|nraw|))
  const float sp = fmaxf(nraw, 0.0f) + log1pf(expf(-fabsf(nraw)));
  const float z  = fmaf(sp, ep, g);

  // top-1 butterfly (all lanes converge)
  float v1 = z; int i1 = lane;
#pragma unroll
  for (int off = 32; off >= 1; off >>= 1) {
    const float ov = __shfl_xor(v1, off, 64);
    const int   oi = __shfl_xor(i1, off, 64);
    if (ov > v1 || (ov == v1 && oi < i1)) { v1 = ov; i1 = oi; }
  }
  // top-2: exclude winner
  float v2 = (lane == i1) ? -INFINITY : z; int i2 = lane;
#pragma unroll
  for (int off = 32; off >= 1; off >>= 1) {
    const float ov = __shfl_xor(v2, off, 64);
    const int   oi = __shfl_xor(i2, off, 64);
    if (ov > v2 || (ov == v2 && oi < i2)) { v2 = ov; i2 = oi; }
  }

  const float e2 = expf(v2 - v1);
  const float denom = 1.0f + e2;
  const float p1 = 1.0f / denom;
  const float p2 = e2 / denom;

  out[PROB_OFF + (size_t)t * EE + lane] =
      (lane == i1) ? p1 : ((lane == i2) ? p2 : 0.0f);

  if (lane == 0) {
    out[IDX_OFF + t * 2 + 0] = (float)i1;
    out[IDX_OFF + t * 2 + 1] = (float)i2;
  }

  out[MASK_OFF + 0 * MASK_K_STRIDE + (size_t)t * EE + lane] = (lane == i1) ? 1.0f : 0.0f;
  out[MASK_OFF + 1 * MASK_K_STRIDE + (size_t)t * EE + lane] = (lane == i2) ? 1.0f : 0.0f;
}

// ---------------------------------------------------------------------------
extern "C" void kernel_launch(void* const* d_in, const int* in_sizes, int n_in,
                              void* d_out, int out_size, void* d_ws, size_t ws_size,
                              hipStream_t stream) {
  const float* x   = (const float*)d_in[0];
  const float* eps = (const float*)d_in[1];
  const float* wg  = (const float*)d_in[2];
  const float* wn  = (const float*)d_in[3];
  float* out = (float*)d_out;
  float* ws  = (float*)d_ws;

  const size_t part_bytes = (size_t)NTOK * 2 * EE * sizeof(float);  // 4 MB/split

  int ksplit;
  if (ws_size >= 4 * part_bytes)      ksplit = 4;   // 16 MB (known to fit)
  else                                ksplit = 2;

  if (ksplit == 4) {
    // 512 token-groups (16 tok/block) x 4 splits = 2048 blocks, 8192 waves
    router_gemm<4, 4, 16><<<dim3(NTOK / 16, 4), dim3(256), 0, stream>>>(x, wg, wn, ws);
  } else {
    router_gemm<2, 4, 16><<<dim3(NTOK / 16, 2), dim3(256), 0, stream>>>(x, wg, wn, ws);
  }

  router_epilogue<<<dim3(NTOK / 4), dim3(256), 0, stream>>>(ws, eps, out, ksplit);
}

// Round 7
// 243.979 us; speedup vs baseline: 1.4609x; 1.4609x over previous
//
#include <hip/hip_runtime.h>
#include <math.h>

// Problem constants
#define DD      2048
#define EE      64
#define NTOK    8192
#define KSPLIT  4
#define KR      (DD / KSPLIT)   // 512
#define KC      32              // k per macro-iteration (staged x tile)
#define NMACRO  (KR / KC)       // 16
#define XSTRIDE 34              // LDS x row stride in words (pad: conflict-free b64 reads)

// Output layout (all read back as float32 by harness):
#define PROB_OFF 0
#define IDX_OFF  524288
#define MASK_OFF 540672
#define MASK_K_STRIDE (NTOK * EE)

// ---------------------------------------------------------------------------
// GEMM, canonical LDS-staged structure (m97-style 2-barrier K-loop).
// Block = 128 thr = 2 waves. Block tile: 16 tokens x 128 cols.
//   wave 0 -> w_gate cols 0..63, wave 1 -> w_noise cols 0..63.
//   lane = tl(3b) x cl(3b): tl = token-lane (2 tokens), cl = col-lane (8 cols).
// x: global -> LDS (2 KB/macro staged cooperatively; deep vmcnt pipeline:
//    the float4 staging load for macro m+1 issues before macro m's compute),
//    consumed as b64 multicast reads (8 lanes/address, padded stride -> no
//    bank conflicts). w: global b128 chunks, L1-hot (16 KB/macro, shared by
//    all resident blocks on the CU since blockIdx.y=ks is the slow grid dim).
// Per 4-k chunk per wave: 64 v_fma + 8 global b128 + 4 ds_read_b64.
// Even fully serialized chunk waits give 37% duty -> 4 waves/SIMD saturate.
// ---------------------------------------------------------------------------
__global__ __launch_bounds__(128, 4) void router_gemm(
    const float* __restrict__ x,        // [NTOK][DD]
    const float* __restrict__ w_gate,   // [DD][EE]
    const float* __restrict__ w_noise,  // [DD][EE]
    float* __restrict__ part)           // [NTOK][KSPLIT][2*EE]
{
  __shared__ float xs_lds[16 * XSTRIDE];

  const int tid  = threadIdx.x;        // 0..127
  const int wid  = tid >> 6;           // 0..1 : which matrix
  const int lane = tid & 63;
  const int tl   = lane >> 3;          // 0..7 token-lane
  const int cl   = lane & 7;           // 0..7 col-lane (8 cols each)

  const int tok0 = blockIdx.x * 16;
  const int ks   = blockIdx.y;
  const int k0   = ks * KR;

  const float* __restrict__ W = (wid ? w_noise : w_gate) + 8 * cl;

  // staging role: stok = token row (0..15), sg = 4-k group (0..7)
  const int stok = tid >> 3;
  const int sg   = tid & 7;
  const float* __restrict__ xsrc =
      x + (size_t)(tok0 + stok) * DD + k0 + 4 * sg;

  float acc[2][8];
#pragma unroll
  for (int tt = 0; tt < 2; ++tt)
#pragma unroll
    for (int e = 0; e < 8; ++e) acc[tt][e] = 0.0f;

  // ---- prologue: stage macro 0 ----
  float4 stg = *reinterpret_cast<const float4*>(xsrc);
  {
    float2* dst = reinterpret_cast<float2*>(&xs_lds[stok * XSTRIDE + 4 * sg]);
    dst[0] = make_float2(stg.x, stg.y);
    dst[1] = make_float2(stg.z, stg.w);
  }
  __syncthreads();

  for (int m = 0; m < NMACRO; ++m) {
    // issue next macro's staging load NOW (consumed ~2000 cycles later)
    if (m + 1 < NMACRO)
      stg = *reinterpret_cast<const float4*>(xsrc + (m + 1) * KC);

    const float* __restrict__ Wm = W + (size_t)(k0 + m * KC) * EE;

#pragma unroll
    for (int c = 0; c < KC / 4; ++c) {           // 8 chunks of 4 k
      // w: 8 independent b128 loads (4 k-rows x 2 halves of this lane's 8 cols)
      float4 wv[4][2];
#pragma unroll
      for (int u = 0; u < 4; ++u) {
        const float* wr = Wm + (size_t)(4 * c + u) * EE;
        wv[u][0] = *reinterpret_cast<const float4*>(wr);
        wv[u][1] = *reinterpret_cast<const float4*>(wr + 4);
      }
      // x: 4 b64 multicast LDS reads (2 tokens x 2 k-pairs)
      float2 xv[2][2];
#pragma unroll
      for (int tt = 0; tt < 2; ++tt)
#pragma unroll
        for (int p = 0; p < 2; ++p)
          xv[tt][p] = *reinterpret_cast<const float2*>(
              &xs_lds[(2 * tl + tt) * XSTRIDE + 4 * c + 2 * p]);
      // 64 scalar v_fma
#pragma unroll
      for (int tt = 0; tt < 2; ++tt)
#pragma unroll
        for (int u = 0; u < 4; ++u) {
          const float xsv = (u & 1) ? xv[tt][u >> 1].y : xv[tt][u >> 1].x;
          const float4 w0 = wv[u][0];
          const float4 w1 = wv[u][1];
          acc[tt][0] = fmaf(xsv, w0.x, acc[tt][0]);
          acc[tt][1] = fmaf(xsv, w0.y, acc[tt][1]);
          acc[tt][2] = fmaf(xsv, w0.z, acc[tt][2]);
          acc[tt][3] = fmaf(xsv, w0.w, acc[tt][3]);
          acc[tt][4] = fmaf(xsv, w1.x, acc[tt][4]);
          acc[tt][5] = fmaf(xsv, w1.y, acc[tt][5]);
          acc[tt][6] = fmaf(xsv, w1.z, acc[tt][6]);
          acc[tt][7] = fmaf(xsv, w1.w, acc[tt][7]);
        }
    }
    __syncthreads();                 // everyone done reading xs_lds
    if (m + 1 < NMACRO) {
      float2* dst = reinterpret_cast<float2*>(&xs_lds[stok * XSTRIDE + 4 * sg]);
      dst[0] = make_float2(stg.x, stg.y);
      dst[1] = make_float2(stg.z, stg.w);
    }
    __syncthreads();                 // new tile visible
  }

  // store partials: token-major [NTOK][KSPLIT][128]; gate cols 0..63, noise 64..127
#pragma unroll
  for (int tt = 0; tt < 2; ++tt) {
    const int tok = tok0 + 2 * tl + tt;
    float* o = part + ((size_t)tok * KSPLIT + ks) * (2 * EE) + wid * EE + 8 * cl;
    float4 a0 = {acc[tt][0], acc[tt][1], acc[tt][2], acc[tt][3]};
    float4 a1 = {acc[tt][4], acc[tt][5], acc[tt][6], acc[tt][7]};
    *reinterpret_cast<float4*>(o)     = a0;
    *reinterpret_cast<float4*>(o + 4) = a1;
  }
}

// ---------------------------------------------------------------------------
// Epilogue: one wave per token. Sum ksplit partials (contiguous per token),
// softplus-noise, top-2 (jax tie semantics: desc value, asc index), softmax
// over 2, scatter probs + indices + one-hot masks.
// ---------------------------------------------------------------------------
__global__ __launch_bounds__(256) void router_epilogue(
    const float* __restrict__ part,      // [NTOK][KSPLIT][2*EE]
    const float* __restrict__ noise_eps, // [NTOK][EE]
    float* __restrict__ out)
{
  const int t    = blockIdx.x * 4 + (threadIdx.x >> 6);
  const int lane = threadIdx.x & 63;

  const float* p = part + (size_t)t * KSPLIT * (2 * EE);
  float g = 0.0f, nraw = 0.0f;
#pragma unroll
  for (int s = 0; s < KSPLIT; ++s) {
    g    += p[s * (2 * EE) + lane];
    nraw += p[s * (2 * EE) + EE + lane];
  }
  const float ep = noise_eps[(size_t)t * EE + lane];

  const float sp = fmaxf(nraw, 0.0f) + log1pf(expf(-fabsf(nraw)));
  const float z  = fmaf(sp, ep, g);

  float v1 = z; int i1 = lane;
#pragma unroll
  for (int off = 32; off >= 1; off >>= 1) {
    const float ov = __shfl_xor(v1, off, 64);
    const int   oi = __shfl_xor(i1, off, 64);
    if (ov > v1 || (ov == v1 && oi < i1)) { v1 = ov; i1 = oi; }
  }
  float v2 = (lane == i1) ? -INFINITY : z; int i2 = lane;
#pragma unroll
  for (int off = 32; off >= 1; off >>= 1) {
    const float ov = __shfl_xor(v2, off, 64);
    const int   oi = __shfl_xor(i2, off, 64);
    if (ov > v2 || (ov == v2 && oi < i2)) { v2 = ov; i2 = oi; }
  }

  const float e2 = expf(v2 - v1);
  const float denom = 1.0f + e2;
  const float p1 = 1.0f / denom;
  const float p2 = e2 / denom;

  out[PROB_OFF + (size_t)t * EE + lane] =
      (lane == i1) ? p1 : ((lane == i2) ? p2 : 0.0f);

  if (lane == 0) {
    out[IDX_OFF + t * 2 + 0] = (float)i1;
    out[IDX_OFF + t * 2 + 1] = (float)i2;
  }

  out[MASK_OFF + 0 * MASK_K_STRIDE + (size_t)t * EE + lane] = (lane == i1) ? 1.0f : 0.0f;
  out[MASK_OFF + 1 * MASK_K_STRIDE + (size_t)t * EE + lane] = (lane == i2) ? 1.0f : 0.0f;
}

// ---------------------------------------------------------------------------
extern "C" void kernel_launch(void* const* d_in, const int* in_sizes, int n_in,
                              void* d_out, int out_size, void* d_ws, size_t ws_size,
                              hipStream_t stream) {
  const float* x   = (const float*)d_in[0];
  const float* eps = (const float*)d_in[1];
  const float* wg  = (const float*)d_in[2];
  const float* wn  = (const float*)d_in[3];
  float* out = (float*)d_out;
  float* ws  = (float*)d_ws;   // needs KSPLIT*4MB = 16 MB (fits: R3 confirmed >=16MB)

  // grid: blockIdx.x = token tile (fast; same ks share w slice), .y = k-split
  router_gemm<<<dim3(NTOK / 16, KSPLIT), dim3(128), 0, stream>>>(x, wg, wn, ws);
  router_epilogue<<<dim3(NTOK / 4), dim3(256), 0, stream>>>(ws, eps, out);
}

// Round 8
// 176.189 us; speedup vs baseline: 2.0231x; 1.3848x over previous
//
#include <hip/hip_runtime.h>
#include <math.h>

// Problem constants
#define DD    2048
#define EE    64
#define NTOK  8192
#define KS    4                 // k-split
#define KR    (DD / KS)         // 512 k per block
#define KC    32                // k per macro-iteration
#define NM    (KR / KC)         // 16 macros
#define TB    64                // tokens per block

// LDS word-offsets (one float = one word)
#define WBUF_WORDS 4100         // 2048 gate + 4 pad (bank shift) + 2048 noise
#define XSTR       36           // x row stride (pad: distinct banks per token-lane)
#define XBUF_WORDS (TB * XSTR)  // 2304
#define XBASE      (2 * WBUF_WORDS)          // 8200
#define LDS_WORDS  (XBASE + 2 * XBUF_WORDS)  // 12808 -> 51232 B

// Output layout (all read back as float32 by harness):
#define PROB_OFF 0
#define IDX_OFF  524288
#define MASK_OFF 540672
#define MASK_K_STRIDE (NTOK * EE)

// ---------------------------------------------------------------------------
// GEMM, full m97 shape: compute reads ONLY LDS (ds_read_b128 -> v_fma, the
// one pattern the compiler demonstrably pipelines with fine-grained lgkmcnt).
// Global traffic is pure staging, prefetched one macro (~2000 cyc) ahead
// into VGPRs, ds_written into the next LDS buffer at iter start.
//
// Block 256 thr = 4 waves; tile 64 tok x 128 cols; wave wid owns tokens
// 16*wid..16*wid+15. lane = tl(2b) x cl(4b): tl -> token (tl + 4*tt),
// cl -> 8 cols (cl 0..7 gate cols 8cl.., cl 8..15 noise cols 8(cl-8)..).
// Per 4-k chunk: 8 w ds_read_b128 (2-way max: noise region offset +4 words
// puts gate/noise on disjoint bank halves) + 4 x ds_read_b128 (XSTR=36 ->
// token-lanes on distinct banks, 16-way cl multicast) + 128 v_fma.
// ---------------------------------------------------------------------------
__global__ __launch_bounds__(256, 4) void router_gemm(
    const float* __restrict__ x,        // [NTOK][DD]
    const float* __restrict__ wg,       // [DD][EE]
    const float* __restrict__ wn,       // [DD][EE]
    float* __restrict__ part)           // [NTOK][KS][2*EE]
{
  __shared__ float lds[LDS_WORDS];

  const int tid  = threadIdx.x;        // 0..255
  const int wid  = tid >> 6;           // 0..3
  const int lane = tid & 63;
  const int tl   = lane >> 4;          // 0..3 token-lane
  const int cl   = lane & 15;          // 0..15 col-lane

  const int tok0 = blockIdx.x * TB;
  const int ks   = blockIdx.y;
  const int k0   = ks * KR;

  // staging roles
  const int xtok = tid >> 3;           // 0..31 (two groups of 32 tokens via j)
  const int xko  = 4 * (tid & 7);      // k-offset within macro

  // compute-role LDS read base for w (word offset inside a w buffer)
  const int wread0 = (cl < 8) ? (8 * cl) : (2052 + 8 * (cl - 8));

  float4 sw[4];   // staged w: j = (mat<<1)|half
  float4 sx[2];   // staged x: j = token-half

  // ---- prologue: load macro 0 ----
#pragma unroll
  for (int j = 0; j < 4; ++j) {
    const float* src = ((j >> 1) ? wn : wg) +
                       (size_t)k0 * EE + (j & 1) * 1024 + 4 * tid;
    sw[j] = *reinterpret_cast<const float4*>(src);
  }
#pragma unroll
  for (int j = 0; j < 2; ++j) {
    const int tok = tok0 + j * 32 + xtok;
    sx[j] = *reinterpret_cast<const float4*>(x + (size_t)tok * DD + k0 + xko);
  }
  // write buffer 0
#pragma unroll
  for (int j = 0; j < 4; ++j) {
    const int dst = ((j >> 1) ? 2052 : 0) + (j & 1) * 1024 + 4 * tid;
    *reinterpret_cast<float4*>(&lds[dst]) = sw[j];
  }
#pragma unroll
  for (int j = 0; j < 2; ++j) {
    const int dst = XBASE + (j * 32 + xtok) * XSTR + xko;
    *reinterpret_cast<float4*>(&lds[dst]) = sx[j];
  }
  // load macro 1
#pragma unroll
  for (int j = 0; j < 4; ++j) {
    const float* src = ((j >> 1) ? wn : wg) +
                       (size_t)(k0 + KC) * EE + (j & 1) * 1024 + 4 * tid;
    sw[j] = *reinterpret_cast<const float4*>(src);
  }
#pragma unroll
  for (int j = 0; j < 2; ++j) {
    const int tok = tok0 + j * 32 + xtok;
    sx[j] = *reinterpret_cast<const float4*>(x + (size_t)tok * DD + k0 + KC + xko);
  }
  __syncthreads();

  float acc[4][8];
#pragma unroll
  for (int tt = 0; tt < 4; ++tt)
#pragma unroll
    for (int e = 0; e < 8; ++e) acc[tt][e] = 0.0f;

  for (int m = 0; m < NM; ++m) {
    const int cb = m & 1;
    const int nb = (m + 1) & 1;

    if (m + 1 < NM) {
      // ds_write staged macro m+1 into buffer nb (waits ~2000-cyc-old loads)
#pragma unroll
      for (int j = 0; j < 4; ++j) {
        const int dst = nb * WBUF_WORDS +
                        ((j >> 1) ? 2052 : 0) + (j & 1) * 1024 + 4 * tid;
        *reinterpret_cast<float4*>(&lds[dst]) = sw[j];
      }
#pragma unroll
      for (int j = 0; j < 2; ++j) {
        const int dst = XBASE + nb * XBUF_WORDS + (j * 32 + xtok) * XSTR + xko;
        *reinterpret_cast<float4*>(&lds[dst]) = sx[j];
      }
      // prefetch macro m+2 (consumed next iteration)
      if (m + 2 < NM) {
        const int kk = k0 + (m + 2) * KC;
#pragma unroll
        for (int j = 0; j < 4; ++j) {
          const float* src = ((j >> 1) ? wn : wg) +
                             (size_t)kk * EE + (j & 1) * 1024 + 4 * tid;
          sw[j] = *reinterpret_cast<const float4*>(src);
        }
#pragma unroll
        for (int j = 0; j < 2; ++j) {
          const int tok = tok0 + j * 32 + xtok;
          sx[j] = *reinterpret_cast<const float4*>(x + (size_t)tok * DD + kk + xko);
        }
      }
      // pin: don't let the allocator sink the prefetch into next iteration
      __builtin_amdgcn_sched_barrier(0);
    }

    // ---- compute macro m from buffer cb (LDS only) ----
    const float* wb = &lds[cb * WBUF_WORDS + wread0];
    const float* xb = &lds[XBASE + cb * XBUF_WORDS + (16 * wid + tl) * XSTR];

#pragma unroll
    for (int c = 0; c < 8; ++c) {               // 8 chunks of 4 k
      float4 wv[4][2];
#pragma unroll
      for (int u = 0; u < 4; ++u) {
        wv[u][0] = *reinterpret_cast<const float4*>(wb + (c * 4 + u) * 64);
        wv[u][1] = *reinterpret_cast<const float4*>(wb + (c * 4 + u) * 64 + 4);
      }
      float4 xv[4];
#pragma unroll
      for (int tt = 0; tt < 4; ++tt)
        xv[tt] = *reinterpret_cast<const float4*>(xb + 4 * tt * XSTR + c * 4);

#pragma unroll
      for (int tt = 0; tt < 4; ++tt) {
#pragma unroll
        for (int u = 0; u < 4; ++u) {
          const float xs = (u == 0) ? xv[tt].x : (u == 1) ? xv[tt].y
                         : (u == 2) ? xv[tt].z : xv[tt].w;
          acc[tt][0] = fmaf(xs, wv[u][0].x, acc[tt][0]);
          acc[tt][1] = fmaf(xs, wv[u][0].y, acc[tt][1]);
          acc[tt][2] = fmaf(xs, wv[u][0].z, acc[tt][2]);
          acc[tt][3] = fmaf(xs, wv[u][0].w, acc[tt][3]);
          acc[tt][4] = fmaf(xs, wv[u][1].x, acc[tt][4]);
          acc[tt][5] = fmaf(xs, wv[u][1].y, acc[tt][5]);
          acc[tt][6] = fmaf(xs, wv[u][1].z, acc[tt][6]);
          acc[tt][7] = fmaf(xs, wv[u][1].w, acc[tt][7]);
        }
      }
    }
    __syncthreads();   // readers of cb done; writers of nb done
  }

  // store partials: [NTOK][KS][128]; cols = 8cl (0..63 gate, 64..120 noise)
#pragma unroll
  for (int tt = 0; tt < 4; ++tt) {
    const int tok = tok0 + 16 * wid + tl + 4 * tt;
    float* o = part + ((size_t)tok * KS + ks) * (2 * EE) + 8 * cl;
    float4 a0 = {acc[tt][0], acc[tt][1], acc[tt][2], acc[tt][3]};
    float4 a1 = {acc[tt][4], acc[tt][5], acc[tt][6], acc[tt][7]};
    *reinterpret_cast<float4*>(o)     = a0;
    *reinterpret_cast<float4*>(o + 4) = a1;
  }
}

// ---------------------------------------------------------------------------
// Epilogue: one wave per token. Sum KS partials (contiguous per token),
// softplus-noise, top-2 (jax tie semantics: desc value, asc index), softmax
// over 2, scatter probs + indices + one-hot masks.
// ---------------------------------------------------------------------------
__global__ __launch_bounds__(256) void router_epilogue(
    const float* __restrict__ part,      // [NTOK][KS][2*EE]
    const float* __restrict__ noise_eps, // [NTOK][EE]
    float* __restrict__ out)
{
  const int t    = blockIdx.x * 4 + (threadIdx.x >> 6);
  const int lane = threadIdx.x & 63;

  const float* p = part + (size_t)t * KS * (2 * EE);
  float g = 0.0f, nraw = 0.0f;
#pragma unroll
  for (int s = 0; s < KS; ++s) {
    g    += p[s * (2 * EE) + lane];
    nraw += p[s * (2 * EE) + EE + lane];
  }
  const float ep = noise_eps[(size_t)t * EE + lane];

  const float sp = fmaxf(nraw, 0.0f) + log1pf(expf(-fabsf(nraw)));
  const float z  = fmaf(sp, ep, g);

  float v1 = z; int i1 = lane;
#pragma unroll
  for (int off = 32; off >= 1; off >>= 1) {
    const float ov = __shfl_xor(v1, off, 64);
    const int   oi = __shfl_xor(i1, off, 64);
    if (ov > v1 || (ov == v1 && oi < i1)) { v1 = ov; i1 = oi; }
  }
  float v2 = (lane == i1) ? -INFINITY : z; int i2 = lane;
#pragma unroll
  for (int off = 32; off >= 1; off >>= 1) {
    const float ov = __shfl_xor(v2, off, 64);
    const int   oi = __shfl_xor(i2, off, 64);
    if (ov > v2 || (ov == v2 && oi < i2)) { v2 = ov; i2 = oi; }
  }

  const float e2 = expf(v2 - v1);
  const float denom = 1.0f + e2;
  const float p1 = 1.0f / denom;
  const float p2 = e2 / denom;

  out[PROB_OFF + (size_t)t * EE + lane] =
      (lane == i1) ? p1 : ((lane == i2) ? p2 : 0.0f);

  if (lane == 0) {
    out[IDX_OFF + t * 2 + 0] = (float)i1;
    out[IDX_OFF + t * 2 + 1] = (float)i2;
  }

  out[MASK_OFF + 0 * MASK_K_STRIDE + (size_t)t * EE + lane] = (lane == i1) ? 1.0f : 0.0f;
  out[MASK_OFF + 1 * MASK_K_STRIDE + (size_t)t * EE + lane] = (lane == i2) ? 1.0f : 0.0f;
}

// ---------------------------------------------------------------------------
extern "C" void kernel_launch(void* const* d_in, const int* in_sizes, int n_in,
                              void* d_out, int out_size, void* d_ws, size_t ws_size,
                              hipStream_t stream) {
  const float* x   = (const float*)d_in[0];
  const float* eps = (const float*)d_in[1];
  const float* wg  = (const float*)d_in[2];
  const float* wn  = (const float*)d_in[3];
  float* out = (float*)d_out;
  float* ws  = (float*)d_ws;   // KS * 4 MB = 16 MB partials (fits: R3+)

  // grid: x = token tile (128), y = k-split (4) -> 512 blocks = 2/CU exact
  router_gemm<<<dim3(NTOK / TB, KS), dim3(256), 0, stream>>>(x, wg, wn, ws);
  router_epilogue<<<dim3(NTOK / 4), dim3(256), 0, stream>>>(ws, eps, out);
}